// Round 1
// baseline (214.097 us; speedup 1.0000x reference)
//
#include <hip/hip_runtime.h>

// out[b,a,c,k] = exp(-2*pi^2*(e_a-e_c)^2) * cos(2*pi*(m_a-m_c)) + diag noise
// e = xc*inv_std, m = xc*mu  (d == 1, nchannel == 3)

static constexpr float KNEG = -19.739208802178716f; // -2*pi^2

__global__ __launch_bounds__(256) void smk_main(
    const float* __restrict__ xc,      // (nb*n, 3)
    const float* __restrict__ mu,      // (3,)
    const float* __restrict__ inv_std, // (3,)
    const float* __restrict__ likerr,  // (3,)
    float* __restrict__ out,           // (nb*n, n, 3)
    int n)
{
    const int blk = blockIdx.x;        // b*n + a
    const int b   = blk / n;
    const int a   = blk - b * n;
    const int rb  = b * n;             // base row index of batch b

    // per-channel params (uniform across block; scalar loads)
    const float is[3]  = { inv_std[0], inv_std[1], inv_std[2] };
    const float muv[3] = { mu[0], mu[1], mu[2] };

    const float* xa = xc + (size_t)(rb + a) * 3;
    const float xav[3] = { xa[0], xa[1], xa[2] };
    float ea[3], ma[3], nz[3];
    #pragma unroll
    for (int k = 0; k < 3; ++k) {
        ea[k] = xav[k] * is[k];
        ma[k] = xav[k] * muv[k];
        float l = fminf(fmaxf(likerr[k], 0.1f), 1.0f);
        nz[k] = 1e-4f + l * l;
    }

    float*       orow = out + (size_t)blk * n * 3;
    const float* xrow = xc  + (size_t)rb  * 3;

    const int ngroups = n >> 2;        // groups of 4 columns (12 floats)
    for (int g = threadIdx.x; g < ngroups; g += blockDim.x) {
        const int c0 = g << 2;

        // load 4 columns x 3 channels = 12 contiguous floats (48B aligned)
        float xv[12];
        {
            const float4* xp = reinterpret_cast<const float4*>(xrow + (size_t)c0 * 3);
            float4 A = xp[0], B = xp[1], Cq = xp[2];
            xv[0]=A.x;  xv[1]=A.y;  xv[2]=A.z;  xv[3]=A.w;
            xv[4]=B.x;  xv[5]=B.y;  xv[6]=B.z;  xv[7]=B.w;
            xv[8]=Cq.x; xv[9]=Cq.y; xv[10]=Cq.z; xv[11]=Cq.w;
        }

        float ov[12];
        #pragma unroll
        for (int j = 0; j < 4; ++j) {
            const int c = c0 + j;
            #pragma unroll
            for (int k = 0; k < 3; ++k) {
                const float x = xv[j*3 + k];
                const float t = ea[k] - x * is[k];   // e_a - e_c
                const float u = ma[k] - x * muv[k];  // m_a - m_c (in revolutions of 2*pi)
                const float ex = __expf(KNEG * t * t);
                // cos(2*pi*u): exact periodic reduction in revolutions
                const float cs = __builtin_amdgcn_cosf(__builtin_amdgcn_fractf(u));
                float r = ex * cs;
                if (c == a) r += nz[k];              // diagonal noise
                ov[j*3 + k] = r;
            }
        }

        float4* dst = reinterpret_cast<float4*>(orow + (size_t)c0 * 3);
        dst[0] = *reinterpret_cast<const float4*>(&ov[0]);
        dst[1] = *reinterpret_cast<const float4*>(&ov[4]);
        dst[2] = *reinterpret_cast<const float4*>(&ov[8]);
    }
}

extern "C" void kernel_launch(void* const* d_in, const int* in_sizes, int n_in,
                              void* d_out, int out_size, void* d_ws, size_t ws_size,
                              hipStream_t stream) {
    const float* xc      = (const float*)d_in[0];
    const float* mu      = (const float*)d_in[1];
    const float* inv_std = (const float*)d_in[2];
    const float* likerr  = (const float*)d_in[3];
    float*       out     = (float*)d_out;

    const int  C = in_sizes[3];                    // nchannel = 3
    const int  D = in_sizes[1] / C;                // ndim = 1
    const long P = (long)in_sizes[0] / ((long)C * D);   // nb*n
    const long n = (long)out_size / (P * C);       // n
    (void)n_in; (void)d_ws; (void)ws_size;

    smk_main<<<dim3((unsigned)P), dim3(256), 0, stream>>>(
        xc, mu, inv_std, likerr, out, (int)n);
}

// Round 2
// 203.647 us; speedup vs baseline: 1.0513x; 1.0513x over previous
//
#include <hip/hip_runtime.h>

// out[b,a,c,k] = exp(-2*pi^2*(e_a-e_c)^2) * cos(2*pi*(m_a-m_c)) + diag noise
// e = xc*inv_std, m = xc*mu  (d == 1, nchannel == 3)
//
// Flat trick: output row (b,a) has flat layout (c,k) identical to xc[b]'s
// (n,3) layout -> element f uses xrow[f], k = f%3, diagonal iff f-3a in [0,3).
// Lane i handles float4 idx = s*256+tid: loads AND stores fully coalesced
// (1KB contiguous per wave store, vs stride-48 fragmentation in R1).

static constexpr float KNEG = -19.739208802178716f; // -2*pi^2

__device__ __forceinline__ float sel3(float p0, float p1, float p2, int k) {
    float r = (k == 1) ? p1 : p0;
    return (k == 2) ? p2 : r;
}

__global__ __launch_bounds__(256) void smk_main(
    const float* __restrict__ xc,      // (nb*n, 3)
    const float* __restrict__ mu,      // (3,)
    const float* __restrict__ inv_std, // (3,)
    const float* __restrict__ likerr,  // (3,)
    float* __restrict__ out,           // (nb*n, n*3)
    int n)
{
    const int blk = blockIdx.x;        // b*n + a
    const int b   = blk / n;
    const int a   = blk - b * n;
    const int rb  = b * n;

    // wave-uniform channel params (scalar loads)
    const float is0 = inv_std[0], is1 = inv_std[1], is2 = inv_std[2];
    const float mu0 = mu[0],      mu1 = mu[1],      mu2 = mu[2];

    const float* xa = xc + (size_t)(rb + a) * 3;
    const float ea0 = xa[0] * is0, ea1 = xa[1] * is1, ea2 = xa[2] * is2;
    const float ma0 = xa[0] * mu0, ma1 = xa[1] * mu1, ma2 = xa[2] * mu2;

    float l0 = fminf(fmaxf(likerr[0], 0.1f), 1.0f);
    float l1 = fminf(fmaxf(likerr[1], 0.1f), 1.0f);
    float l2 = fminf(fmaxf(likerr[2], 0.1f), 1.0f);
    const float nz0 = 1e-4f + l0 * l0;
    const float nz1 = 1e-4f + l1 * l1;
    const float nz2 = 1e-4f + l2 * l2;

    const float4* __restrict__ xrow4 = reinterpret_cast<const float4*>(xc + (size_t)rb * 3);
    float4*       __restrict__ orow4 = reinterpret_cast<float4*>(out + (size_t)blk * n * 3);

    const int nq = (n * 3) >> 2;       // float4s per row (1536 for n=2048)
    const int a3 = 3 * a;

    for (int idx = threadIdx.x; idx < nq; idx += 256) {
        const float4 xq = xrow4[idx];  // coalesced, L2-hot
        const int f0 = idx << 2;
        int k = idx % 3;               // f0 mod 3 (4 == 1 mod 3)

        const float xv[4] = { xq.x, xq.y, xq.z, xq.w };
        float r[4];
        #pragma unroll
        for (int j = 0; j < 4; ++j) {
            const int f = f0 + j;
            const float x   = xv[j];
            const float isk = sel3(is0, is1, is2, k);
            const float muk = sel3(mu0, mu1, mu2, k);
            const float eak = sel3(ea0, ea1, ea2, k);
            const float mak = sel3(ma0, ma1, ma2, k);
            const float t = eak - x * isk;     // e_a - e_c
            const float u = mak - x * muk;     // m_a - m_c (revolutions)
            const float ex = __expf(KNEG * t * t);
            const float cs = __builtin_amdgcn_cosf(__builtin_amdgcn_fractf(u));
            float rr = ex * cs;
            if ((unsigned)(f - a3) < 3u)       // diagonal (c == a)
                rr += sel3(nz0, nz1, nz2, k);
            r[j] = rr;
            k = (k == 2) ? 0 : k + 1;
        }
        orow4[idx] = make_float4(r[0], r[1], r[2], r[3]);
    }
}

extern "C" void kernel_launch(void* const* d_in, const int* in_sizes, int n_in,
                              void* d_out, int out_size, void* d_ws, size_t ws_size,
                              hipStream_t stream) {
    const float* xc      = (const float*)d_in[0];
    const float* mu      = (const float*)d_in[1];
    const float* inv_std = (const float*)d_in[2];
    const float* likerr  = (const float*)d_in[3];
    float*       out     = (float*)d_out;

    const int  C = in_sizes[3];                       // nchannel = 3
    const int  D = in_sizes[1] / C;                   // ndim = 1
    const long P = (long)in_sizes[0] / ((long)C * D); // nb*n
    const long n = (long)out_size / (P * C);          // n
    (void)n_in; (void)d_ws; (void)ws_size;

    smk_main<<<dim3((unsigned)P), dim3(256), 0, stream>>>(
        xc, mu, inv_std, likerr, out, (int)n);
}

// Round 4
// 198.002 us; speedup vs baseline: 1.0813x; 1.0285x over previous
//
#include <hip/hip_runtime.h>

// out[b,a,c,k] = exp(-2*pi^2*(e_a-e_c)^2) * cos(2*pi*(m_a-m_c)) + diag noise
// e = xc*inv_std, m = xc*mu  (d == 1, nchannel == 3)
//
// Layout trick: output row (b,a) flat (c,k) == xc[b] flat (n,3). Each lane
// owns ONE channel-triple (12B): k is compile-time (no cndmask selection),
// and lane stores are still contiguous (64 lanes x 12B = 768B per dwordx3).

static constexpr float KNEG2 = -28.4776592f; // -2*pi^2 * log2(e)

__device__ __forceinline__ float smk_elem(float x, float ea, float is,
                                          float ma, float mu) {
    const float t  = __builtin_fmaf(-is, x, ea);   // e_a - e_c
    const float ex = __builtin_amdgcn_exp2f(t * t * KNEG2);
    const float u  = __builtin_fmaf(-mu, x, ma);   // m_a - m_c (revolutions)
    const float cs = __builtin_amdgcn_cosf(__builtin_amdgcn_fractf(u));
    return ex * cs;
}

__global__ __launch_bounds__(256) void smk_main(
    const float* __restrict__ xc,      // (nb*n, 3)
    const float* __restrict__ mu,      // (3,)
    const float* __restrict__ inv_std, // (3,)
    const float* __restrict__ likerr,  // (3,)
    float* __restrict__ out,           // (nb*n, n*3)
    int n)
{
    const int blk = blockIdx.x;        // b*n + a
    const int b   = blk / n;
    const int a   = blk - b * n;
    const int rb  = b * n;

    // wave-uniform channel params
    const float is0 = inv_std[0], is1 = inv_std[1], is2 = inv_std[2];
    const float mu0 = mu[0],      mu1 = mu[1],      mu2 = mu[2];

    const float* xa = xc + (size_t)(rb + a) * 3;
    const float ea0 = xa[0] * is0, ea1 = xa[1] * is1, ea2 = xa[2] * is2;
    const float ma0 = xa[0] * mu0, ma1 = xa[1] * mu1, ma2 = xa[2] * mu2;

    const float l0 = fminf(fmaxf(likerr[0], 0.1f), 1.0f);
    const float l1 = fminf(fmaxf(likerr[1], 0.1f), 1.0f);
    const float l2 = fminf(fmaxf(likerr[2], 0.1f), 1.0f);
    const float nz0 = 1e-4f + l0 * l0;
    const float nz1 = 1e-4f + l1 * l1;
    const float nz2 = 1e-4f + l2 * l2;

    const float* __restrict__ xrow = xc  + (size_t)rb  * 3;
    float*       __restrict__ orow = out + (size_t)blk * 3 * n;

    #pragma unroll 4
    for (int c = threadIdx.x; c < n; c += 256) {
        const float3 xq = *reinterpret_cast<const float3*>(xrow + 3 * c);

        float r0 = smk_elem(xq.x, ea0, is0, ma0, mu0);
        float r1 = smk_elem(xq.y, ea1, is1, ma1, mu1);
        float r2 = smk_elem(xq.z, ea2, is2, ma2, mu2);

        if (c == a) { r0 += nz0; r1 += nz1; r2 += nz2; }

        *reinterpret_cast<float3*>(orow + 3 * c) = make_float3(r0, r1, r2);
    }
}

extern "C" void kernel_launch(void* const* d_in, const int* in_sizes, int n_in,
                              void* d_out, int out_size, void* d_ws, size_t ws_size,
                              hipStream_t stream) {
    const float* xc      = (const float*)d_in[0];
    const float* mu      = (const float*)d_in[1];
    const float* inv_std = (const float*)d_in[2];
    const float* likerr  = (const float*)d_in[3];
    float*       out     = (float*)d_out;

    const int  C = in_sizes[3];                       // nchannel = 3
    const int  D = in_sizes[1] / C;                   // ndim = 1
    const long P = (long)in_sizes[0] / ((long)C * D); // nb*n
    const long n = (long)out_size / (P * C);          // n
    (void)n_in; (void)d_ws; (void)ws_size;

    smk_main<<<dim3((unsigned)P), dim3(256), 0, stream>>>(
        xc, mu, inv_std, likerr, out, (int)n);
}